// Round 5
// baseline (113.106 us; speedup 1.0000x reference)
//
#include <hip/hip_runtime.h>
#include <hip/hip_bf16.h>

// GAT layer, B=4, N=4096, F_in=128, F_out=64.
// out_i = sum_j adj_ij * exp(leaky(s2_i+s1_j)) * Wh_j
//         / ( sum_j adj_ij*exp(..) + 1e-9 * sum_j exp(..) )
// softmax max-subtraction cancels exactly (num & denom scale by e^m together);
// scores are O(8) so bare exp2 is safe. s1/s2 stored pre-scaled by log2(e).
//
// R5 structure: barrier-free k_main. One wave per 64-thread block, each wave
// owns a 16x64 output tile, builds P directly in MFMA A-fragment registers
// (no LDS at all), loads B (WhT, single bf16) global->VGPR. Depth-1 register
// prefetch, unroll-2; compiler inserts exact per-register vmcnt waits.

typedef __attribute__((ext_vector_type(8))) short bf16x8;
typedef __attribute__((ext_vector_type(4))) float f32x4;
typedef __attribute__((ext_vector_type(4))) unsigned int u32x4;

#define LOG2E 1.4426950408889634f

__device__ __forceinline__ unsigned short f2bf(float x) {
  union { float f; unsigned int u; } c; c.f = x;
  unsigned int r = c.u + 0x7fffu + ((c.u >> 16) & 1u);  // RNE
  return (unsigned short)(r >> 16);
}
__device__ __forceinline__ bf16x8 u2b(u32x4 v) {
  union { u32x4 u; bf16x8 b; } c; c.u = v; return c.b;
}

// ---------------- K1: Wh = h @ W (f32); WhT bf16 [b][64col][4096k];
//                  s1 = Wh a1 * log2e, s2 = Wh a2 * log2e
__global__ __launch_bounds__(256) void k_wh(
    const float* __restrict__ h, const float* __restrict__ W, const float* __restrict__ a,
    unsigned short* __restrict__ wt, float* __restrict__ s1, float* __restrict__ s2) {
  __shared__ float hs[32][130];
  const int t = threadIdx.x;
  const int b = blockIdx.x >> 7;
  const int row0 = (blockIdx.x & 127) << 5;

  #pragma unroll
  for (int it = 0; it < 4; ++it) {
    int flat = it * 256 + t;
    int r = flat >> 5, q = flat & 31;
    const float4 v = *(const float4*)(h + ((size_t)(b * 4096 + row0 + r)) * 128 + 4 * q);
    hs[r][4*q+0] = v.x; hs[r][4*q+1] = v.y; hs[r][4*q+2] = v.z; hs[r][4*q+3] = v.w;
  }
  __syncthreads();

  const int rg = t >> 4, cg = t & 15;
  float acc[2][4] = {};
  for (int k = 0; k < 128; ++k) {
    float4 wv = *(const float4*)(W + k * 64 + 4 * cg);
    #pragma unroll
    for (int i = 0; i < 2; ++i) {
      float hv = hs[2*rg + i][k];
      acc[i][0] = fmaf(hv, wv.x, acc[i][0]);
      acc[i][1] = fmaf(hv, wv.y, acc[i][1]);
      acc[i][2] = fmaf(hv, wv.z, acc[i][2]);
      acc[i][3] = fmaf(hv, wv.w, acc[i][3]);
    }
  }
  __syncthreads();

  float (*WhF)[68] = (float(*)[68])hs;
  #pragma unroll
  for (int i = 0; i < 2; ++i)
    #pragma unroll
    for (int j = 0; j < 4; ++j)
      WhF[2*rg + i][4*cg + j] = acc[i][j];
  __syncthreads();

  if (t < 32) {
    float x1 = 0.f, x2 = 0.f;
    #pragma unroll 8
    for (int c = 0; c < 64; ++c) {
      float v = WhF[t][c];
      x1 = fmaf(v, a[c], x1);
      x2 = fmaf(v, a[64 + c], x2);
    }
    s1[b * 4096 + row0 + t] = x1 * LOG2E;
    s2[b * 4096 + row0 + t] = x2 * LOG2E;
  }

  const int col = t >> 2, sub = t & 3;
  unsigned int uh[4];
  #pragma unroll
  for (int r = 0; r < 4; ++r) {
    unsigned short h0 = f2bf(WhF[8*sub + 2*r][col]);
    unsigned short h1 = f2bf(WhF[8*sub + 2*r + 1][col]);
    uh[r] = (unsigned)h0 | ((unsigned)h1 << 16);
  }
  size_t base = ((size_t)(b * 64 + col)) * 4096 + row0 + 8 * sub;
  *(uint4*)(wt + base) = make_uint4(uh[0], uh[1], uh[2], uh[3]);
}

// ---------------- K3: out = P @ Wh, P built in-register as A-fragments.
// 1024 blocks x 64 threads; block = 1 wave = 16 rows x 64 cols.
// Zero LDS, zero barriers. Lane l: P row = l&15, k-chunks 8*(l>>4)(+32).
__global__ __launch_bounds__(64) void k_main(
    const float* __restrict__ adj, const unsigned short* __restrict__ wt,
    const float* __restrict__ s1, const float* __restrict__ s2,
    float* __restrict__ out) {
  const int l = threadIdx.x;
  const int blk = blockIdx.x;
  // XCD mapping: blk&7 = XCD (default round-robin); 2 XCDs per batch b
  // -> WhT slice 512KB, L2-resident per XCD.
  const int b = (blk & 7) >> 1;
  const int tidx = (blk >> 3) + ((blk & 1) << 7);   // 0..255, bijective
  const int row0 = tidx << 4;
  const int lr = l & 15, g = l >> 4;

  const float* adjBase = adj + ((size_t)(b * 4096 + row0 + lr)) * 4096 + 8 * g;
  const float* s1Base = s1 + b * 4096 + 8 * g;
  const float s2v = s2[b * 4096 + row0 + lr];
  const unsigned short* wtB = wt + ((size_t)(b * 64 + lr)) * 4096 + 8 * g;

  float z = 0.f, sa = 0.f;
  f32x4 acc[4] = {{0.f,0.f,0.f,0.f},{0.f,0.f,0.f,0.f},{0.f,0.f,0.f,0.f},{0.f,0.f,0.f,0.f}};

#define LOADSET(av, sv, bv, ks) do {                                          \
    const int ko = ((ks) & 63) << 6;                                          \
    av[0] = *(const f32x4*)(adjBase + ko);                                    \
    av[1] = *(const f32x4*)(adjBase + ko + 4);                                \
    av[2] = *(const f32x4*)(adjBase + ko + 32);                               \
    av[3] = *(const f32x4*)(adjBase + ko + 36);                               \
    sv[0] = *(const f32x4*)(s1Base + ko);                                     \
    sv[1] = *(const f32x4*)(s1Base + ko + 4);                                 \
    sv[2] = *(const f32x4*)(s1Base + ko + 32);                                \
    sv[3] = *(const f32x4*)(s1Base + ko + 36);                                \
    _Pragma("unroll")                                                         \
    for (int cg = 0; cg < 4; ++cg) {                                          \
      bv[2*cg]   = *(const u32x4*)(wtB + cg * 65536 + ko);                    \
      bv[2*cg+1] = *(const u32x4*)(wtB + cg * 65536 + ko + 32);               \
    }                                                                         \
  } while (0)

#define STEPX(av, sv, bv) do {                                                \
    bf16x8 fr0, fr1;                                                          \
    _Pragma("unroll")                                                         \
    for (int kk = 0; kk < 2; ++kk) {                                          \
      unsigned int pk[4];                                                     \
      _Pragma("unroll")                                                       \
      for (int q = 0; q < 4; ++q) {                                           \
        float e0 = s2v + sv[2*kk + (q>>1)][(q&1)*2 + 0];                      \
        float e1 = s2v + sv[2*kk + (q>>1)][(q&1)*2 + 1];                      \
        e0 = fmaxf(e0, 0.2f*e0); e1 = fmaxf(e1, 0.2f*e1);                     \
        float p0 = exp2f(e0), p1 = exp2f(e1);                                 \
        float w0 = av[2*kk + (q>>1)][(q&1)*2 + 0] * p0;                       \
        float w1 = av[2*kk + (q>>1)][(q&1)*2 + 1] * p1;                       \
        z += p0 + p1; sa += w0 + w1;                                          \
        pk[q] = (unsigned)f2bf(w0) | ((unsigned)f2bf(w1) << 16);              \
      }                                                                       \
      union { unsigned int s[4]; u32x4 v; } fu;                               \
      fu.s[0] = pk[0]; fu.s[1] = pk[1]; fu.s[2] = pk[2]; fu.s[3] = pk[3];     \
      if (kk == 0) fr0 = u2b(fu.v); else fr1 = u2b(fu.v);                     \
    }                                                                         \
    _Pragma("unroll")                                                         \
    for (int cg = 0; cg < 4; ++cg) {                                          \
      acc[cg] = __builtin_amdgcn_mfma_f32_16x16x32_bf16(fr0, u2b(bv[2*cg]),   \
                                                        acc[cg], 0, 0, 0);    \
      acc[cg] = __builtin_amdgcn_mfma_f32_16x16x32_bf16(fr1, u2b(bv[2*cg+1]), \
                                                        acc[cg], 0, 0, 0);    \
    }                                                                         \
  } while (0)

  f32x4 aA[4], sAv[4]; u32x4 bA[8];
  f32x4 aB[4], sBv[4]; u32x4 bB[8];

  LOADSET(aA, sAv, bA, 0);                 // step 0 operands
  for (int it = 0; it < 32; ++it) {
    LOADSET(aB, sBv, bB, 2*it + 1);        // issue step 2it+1 (in flight over STEPX A)
    STEPX(aA, sAv, bA);                    // consume step 2it
    LOADSET(aA, sAv, bA, 2*it + 2);        // issue step 2it+2 (wraps harmlessly at end)
    STEPX(aB, sBv, bB);                    // consume step 2it+1
  }

  // row sums: reduce over the 4 lane-groups sharing a row (xor 16, 32)
  z += __shfl_xor(z, 16);  z += __shfl_xor(z, 32);
  sa += __shfl_xor(sa, 16); sa += __shfl_xor(sa, 32);
  const float inv = 1.0f / (sa + 1e-9f * z);   // lane l holds row l&15's scale

  // epilogue: C layout col=l&15, row=4*(l>>4)+reg
  #pragma unroll
  for (int reg = 0; reg < 4; ++reg) {
    const float invr = __shfl(inv, 4 * g + reg);
    const size_t ob = ((size_t)(b * 4096 + row0 + 4 * g + reg)) * 64 + lr;
    #pragma unroll
    for (int cg = 0; cg < 4; ++cg)
      out[ob + 16 * cg] = acc[cg][reg] * invr;
  }
}

extern "C" void kernel_launch(void* const* d_in, const int* in_sizes, int n_in,
                              void* d_out, int out_size, void* d_ws, size_t ws_size,
                              hipStream_t stream) {
  const float* h   = (const float*)d_in[0];
  const float* adj = (const float*)d_in[1];
  const float* W   = (const float*)d_in[2];
  const float* a   = (const float*)d_in[3];
  float* out = (float*)d_out;

  // ws layout: WhT (2MB bf16) | s1 (64KB) | s2 (64KB)
  unsigned short* wt = (unsigned short*)d_ws;
  float* s1 = (float*)(wt + (size_t)4 * 64 * 4096);
  float* s2 = s1 + 16384;

  k_wh  <<<512, 256, 0, stream>>>(h, W, a, wt, s1, s2);
  k_main<<<1024, 64, 0, stream>>>(adj, wt, s1, s2, out);
}